// Round 1
// baseline (201.492 us; speedup 1.0000x reference)
//
#include <hip/hip_runtime.h>
#include <math.h>

constexpr int C  = 128;
constexpr int H  = 128;
constexpr int Wd = 128;
constexpr int HW = H * Wd;
constexpr int LH = 64, LW = 64;

// ---------------------------------------------------------------------------
// Kernel 1: bilinear upsample (align_corners=True) -> lr_up (written to d_out)
//           + depthwise 3x3 conv -> q.  One block = one (n,c) 16x16 tile.
// ---------------------------------------------------------------------------
__global__ __launch_bounds__(256) void k_lrup_q(
    const float* __restrict__ lr, const float* __restrict__ wq,
    const float* __restrict__ bq, float* __restrict__ lrup_out,
    float* __restrict__ qout)
{
  __shared__ float tile[18][18];
  const int nc = blockIdx.z;              // n*C + c
  const float* src = lr + nc * (LH * LW);
  const float scale = 63.0f / 127.0f;

  for (int h = threadIdx.x; h < 18 * 18; h += 256) {
    const int hy = h / 18, hx = h - hy * 18;
    const int gy = blockIdx.y * 16 + hy - 1;
    const int gx = blockIdx.x * 16 + hx - 1;
    float val = 0.f;
    if (gy >= 0 && gy < H && gx >= 0 && gx < Wd) {
      const float fy = gy * scale, fx = gx * scale;
      const int y0 = (int)fy, x0 = (int)fx;
      const float wy = fy - y0, wx = fx - x0;
      const int y1 = min(y0 + 1, LH - 1), x1 = min(x0 + 1, LW - 1);
      const float* r0 = src + y0 * LW;
      const float* r1 = src + y1 * LW;
      const float a = r0[x0], b = r0[x1], c2 = r1[x0], d = r1[x1];
      const float t0 = a + (b - a) * wx;
      const float t1 = c2 + (d - c2) * wx;
      val = t0 + (t1 - t0) * wy;
    }
    tile[hy][hx] = val;
  }
  __syncthreads();

  const int tx = threadIdx.x & 15, ty = threadIdx.x >> 4;
  const int c = nc & (C - 1);
  const float* wc = wq + c * 9;
  float acc = bq[c];
#pragma unroll
  for (int i = 0; i < 3; i++)
#pragma unroll
    for (int j = 0; j < 3; j++)
      acc += wc[i * 3 + j] * tile[ty + i][tx + j];

  const int gy = blockIdx.y * 16 + ty, gx = blockIdx.x * 16 + tx;
  lrup_out[nc * HW + gy * Wd + gx] = tile[ty + 1][tx + 1];
  qout[nc * HW + gy * Wd + gx] = acc;
}

// ---------------------------------------------------------------------------
// Kernel 2: depthwise 3x3 convs on hr_feat -> k and v (shared staged tile)
// ---------------------------------------------------------------------------
__global__ __launch_bounds__(256) void k_kv(
    const float* __restrict__ hr, const float* __restrict__ wk,
    const float* __restrict__ bk, const float* __restrict__ wv,
    const float* __restrict__ bv, float* __restrict__ kout,
    float* __restrict__ vout)
{
  __shared__ float tile[18][18];
  const int nc = blockIdx.z;
  const float* src = hr + nc * HW;

  for (int h = threadIdx.x; h < 18 * 18; h += 256) {
    const int hy = h / 18, hx = h - hy * 18;
    const int gy = blockIdx.y * 16 + hy - 1;
    const int gx = blockIdx.x * 16 + hx - 1;
    tile[hy][hx] = (gy >= 0 && gy < H && gx >= 0 && gx < Wd)
                       ? src[gy * Wd + gx] : 0.f;
  }
  __syncthreads();

  const int tx = threadIdx.x & 15, ty = threadIdx.x >> 4;
  const int c = nc & (C - 1);
  const float* wkc = wk + c * 9;
  const float* wvc = wv + c * 9;
  float ak = bk[c], av = bv[c];
#pragma unroll
  for (int i = 0; i < 3; i++)
#pragma unroll
    for (int j = 0; j < 3; j++) {
      const float t = tile[ty + i][tx + j];
      ak += wkc[i * 3 + j] * t;
      av += wvc[i * 3 + j] * t;
    }
  const int gy = blockIdx.y * 16 + ty, gx = blockIdx.x * 16 + tx;
  kout[nc * HW + gy * Wd + gx] = ak;
  vout[nc * HW + gy * Wd + gx] = av;
}

// ---------------------------------------------------------------------------
// Kernel 3: gating conv 3x3, in=[q;k] (256 ch) -> 2 ch, channel-split 8 ways.
// Writes partial sums; kernel 4 finishes (+ba, sigmoid).
// grid (2, 32, N*8), block (64,4): one thread per pixel, 32 in-channels.
// ---------------------------------------------------------------------------
__global__ __launch_bounds__(256) void k_dyn(
    const float* __restrict__ q, const float* __restrict__ kbuf,
    const float* __restrict__ wa, float* __restrict__ part)
{
  __shared__ float wsh[576];  // [o][cf_local][tap] = o*288 + cf*9 + t
  const int cs = blockIdx.z & 7, n = blockIdx.z >> 3;
  const int tid = threadIdx.y * 64 + threadIdx.x;
  for (int i = tid; i < 576; i += 256) {
    const int o = i / 288, r = i - o * 288;
    wsh[i] = wa[o * 2304 + cs * 288 + r];
  }
  __syncthreads();

  const int x = blockIdx.x * 64 + threadIdx.x;
  const int y = blockIdx.y * 4 + threadIdx.y;
  float a0 = 0.f, a1 = 0.f;

  for (int i = 0; i < 32; i++) {
    const int cf = cs * 32 + i;
    const float* src = (cf < C) ? (q + (n * C + cf) * HW)
                                : (kbuf + (n * C + cf - C) * HW);
    float t[9];
#pragma unroll
    for (int dy = 0; dy < 3; dy++) {
      const int yy = y + dy - 1;
      const bool oky = (yy >= 0 && yy < H);
      const int ycl = min(max(yy, 0), H - 1);
#pragma unroll
      for (int dx = 0; dx < 3; dx++) {
        const int xx = x + dx - 1;
        const bool okx = (xx >= 0 && xx < Wd);
        const int xcl = min(max(xx, 0), Wd - 1);
        t[dy * 3 + dx] = (oky && okx) ? src[ycl * Wd + xcl] : 0.f;
      }
    }
#pragma unroll
    for (int tt = 0; tt < 9; tt++) {
      a0 += wsh[i * 9 + tt] * t[tt];
      a1 += wsh[288 + i * 9 + tt] * t[tt];
    }
  }
  const int p = y * Wd + x;
  part[((n * 8 + cs) * 2 + 0) * HW + p] = a0;
  part[((n * 8 + cs) * 2 + 1) * HW + p] = a1;
}

// ---------------------------------------------------------------------------
// Kernel 4: 5x5 window attention.
// Block = 32 pixels x 8 channel-groups (16 ch each).
// pass1: partial sim[25] per thread -> LDS reduce -> softmax -> weights.
// pass2: out = lr_up + d0 * sum_k w_k * v[p+off_k] + d1 * v[p]
// grid (4, 128, 2), block 256.
// ---------------------------------------------------------------------------
__global__ __launch_bounds__(256) void k_attn(
    const float* __restrict__ q, const float* __restrict__ kbuf,
    const float* __restrict__ vbuf, const float* __restrict__ part,
    const float* __restrict__ ba, float* __restrict__ outb)
{
  __shared__ float red[25 * 256];   // 25.6 KB
  __shared__ float dsh[2][32];

  const int tid = threadIdx.x;
  const int px = tid & 31, cg = tid >> 5;
  const int x = blockIdx.x * 32 + px;
  const int y = blockIdx.y;
  const int n = blockIdx.z;
  const int p = y * Wd + x;

  // finish gating: sum 8 partials + bias, sigmoid
  if (tid < 64) {
    const int o = tid >> 5, lx = tid & 31;
    const int pp = y * Wd + blockIdx.x * 32 + lx;
    float s = ba[o];
#pragma unroll
    for (int cs = 0; cs < 8; cs++)
      s += part[((n * 8 + cs) * 2 + o) * HW + pp];
    dsh[o][lx] = 1.f / (1.f + expf(-s));
  }

  // window offsets (clamped, always in-bounds) + validity mask (zero-pad)
  int aoff[25];
  unsigned mask = 0;
#pragma unroll
  for (int i = 0; i < 5; i++) {
    const int yy = y + i - 2;
    const int yc = min(max(yy, 0), H - 1);
#pragma unroll
    for (int j = 0; j < 5; j++) {
      const int xx = x + j - 2;
      const int xc = min(max(xx, 0), Wd - 1);
      aoff[i * 5 + j] = yc * Wd + xc;
      if (yy >= 0 && yy < H && xx >= 0 && xx < Wd) mask |= 1u << (i * 5 + j);
    }
  }

  float sim[25];
#pragma unroll
  for (int k = 0; k < 25; k++) sim[k] = 0.f;

  const int cbase = (n * C + cg * 16) * HW;
  const float* qp = q + cbase + p;
  const float* kp = kbuf + cbase;
  for (int ci = 0; ci < 16; ci++) {
    const float qv = qp[ci * HW];
#pragma unroll
    for (int k = 0; k < 25; k++) {
      const float kv = ((mask >> k) & 1) ? kp[ci * HW + aoff[k]] : 0.f;
      sim[k] += qv * kv;
    }
  }

#pragma unroll
  for (int k = 0; k < 25; k++) red[k * 256 + tid] = sim[k];
  __syncthreads();

  // 8-way cross-channel-group reduction: thread (k mod 8 == cg, px)
  for (int k = cg; k < 25; k += 8) {
    float s = 0.f;
#pragma unroll
    for (int g = 0; g < 8; g++) s += red[k * 256 + g * 32 + px];
    red[k * 256 + px] = s;   // slot g=0; only this thread touches it
  }
  __syncthreads();

  // softmax over 25 per pixel (threads 0..31)
  if (tid < 32) {
    float sv[25], m = -1e30f;
#pragma unroll
    for (int k = 0; k < 25; k++) {
      sv[k] = red[k * 256 + tid];
      m = fmaxf(m, sv[k]);
    }
    float tot = 0.f;
#pragma unroll
    for (int k = 0; k < 25; k++) {
      const float e = expf(sv[k] - m);
      sv[k] = e;
      tot += e;
    }
    const float inv = 1.f / tot;
#pragma unroll
    for (int k = 0; k < 25; k++) red[k * 256 + tid] = sv[k] * inv;
  }
  __syncthreads();

  float w[25];
#pragma unroll
  for (int k = 0; k < 25; k++) w[k] = red[k * 256 + px];
  const float d0 = dsh[0][px], d1 = dsh[1][px];

  const float* vp = vbuf + cbase;
  float* op = outb + cbase + p;
  for (int ci = 0; ci < 16; ci++) {
    float acc = 0.f, vc = 0.f;
#pragma unroll
    for (int k = 0; k < 25; k++) {
      const float val = ((mask >> k) & 1) ? vp[ci * HW + aoff[k]] : 0.f;
      acc += w[k] * val;
      if (k == 12) vc = val;
    }
    op[ci * HW] = op[ci * HW] + d0 * acc + d1 * vc;  // op holds lr_up
  }
}

// ---------------------------------------------------------------------------
extern "C" void kernel_launch(void* const* d_in, const int* in_sizes, int n_in,
                              void* d_out, int out_size, void* d_ws,
                              size_t ws_size, hipStream_t stream)
{
  const float* hr = (const float*)d_in[0];
  const float* lr = (const float*)d_in[1];
  const float* wq = (const float*)d_in[2];
  const float* bq = (const float*)d_in[3];
  const float* wk = (const float*)d_in[4];
  const float* bk = (const float*)d_in[5];
  const float* wv = (const float*)d_in[6];
  const float* bv = (const float*)d_in[7];
  const float* wa = (const float*)d_in[8];
  const float* ba = (const float*)d_in[9];

  float* out = (float*)d_out;
  float* ws  = (float*)d_ws;

  const int NCHW = 2 * C * HW;           // 4194304 floats
  float* qb   = ws;
  float* kb   = qb + NCHW;
  float* vb   = kb + NCHW;
  float* partb = vb + NCHW;              // 2*8*2*HW = 524288 floats

  k_lrup_q<<<dim3(8, 8, 2 * C), dim3(256), 0, stream>>>(lr, wq, bq, out, qb);
  k_kv<<<dim3(8, 8, 2 * C), dim3(256), 0, stream>>>(hr, wk, bk, wv, bv, kb, vb);
  k_dyn<<<dim3(2, 32, 16), dim3(64, 4), 0, stream>>>(qb, kb, wa, partb);
  k_attn<<<dim3(4, 128, 2), dim3(256), 0, stream>>>(qb, kb, vb, partb, ba, out);
}